// Round 15
// baseline (381.293 us; speedup 1.0000x reference)
//
#include <hip/hip_runtime.h>

// ---------------- problem constants ----------------
static constexpr int N_NODES = 100000;
static constexpr int N_EDGES = 3200000;
static constexpr int SHIFT  = 10;                         // 1024 nodes / bucket
static constexpr int NPB    = 1 << SHIFT;                 // 1024
static constexpr int NBK    = (N_NODES + NPB - 1) / NPB;  // 98 buckets
static constexpr int SLOTS  = NBK * NPB;                  // 100352
static constexpr int WGC    = 1000;                       // partition workgroups
static constexpr int CHUNK  = N_EDGES / WGC;              // 3200 edges / WG (exact)
static constexpr int PSPLIT = 8;                          // spans per bucket in reduce

// ---------------- bf16 helpers ----------------
__device__ __forceinline__ unsigned bf16rne(float f) {
    unsigned u = __float_as_uint(f);
    u += 0x7fffu + ((u >> 16) & 1u);
    return u >> 16;
}
__device__ __forceinline__ unsigned pack2(float lo, float hi) {
    return bf16rne(lo) | (bf16rne(hi) << 16);
}
__device__ __forceinline__ float lo16(unsigned w) { return __uint_as_float(w << 16); }
__device__ __forceinline__ float hi16(unsigned w) { return __uint_as_float(w & 0xffff0000u); }

// ---- K_A: import boo (d_in, slow path) -> bf16 copy in d_ws. Pays the d_in
//      read toll ONCE. Thread t: one float4 -> 4 bf16 (8B). Fully dense.
__global__ void __launch_bounds__(256) k_import_boo(
    const float4* __restrict__ boo, uint2* __restrict__ booB)
{
    int t = blockIdx.x * 256 + threadIdx.x;
    if (t >= N_EDGES * 4) return;
    float4 v = boo[t];
    booB[t] = make_uint2(pack2(v.x, v.y), pack2(v.z, v.w));
}

// ---- K_X: import x -> ws (1.6 MB, trivial)
__global__ void __launch_bounds__(256) k_import_x(
    const float4* __restrict__ x, float4* __restrict__ xW)
{
    int t = blockIdx.x * 256 + threadIdx.x;
    if (t < N_NODES) xW[t] = x[t];
}

// ---- K1: histograms for both keys + copy idx to ws (d_in idx read once).
__global__ void __launch_bounds__(256) k_count(
    const int* __restrict__ row, const int* __restrict__ col,
    int* __restrict__ rowW, int* __restrict__ colW,
    unsigned* __restrict__ cmC, unsigned* __restrict__ cmR)
{
    __shared__ unsigned hC[NBK], hR[NBK];
    if (threadIdx.x < NBK) { hC[threadIdx.x] = 0u; hR[threadIdx.x] = 0u; }
    __syncthreads();
    int w = blockIdx.x, e0 = w * CHUNK;
    for (int e = e0 + threadIdx.x; e < e0 + CHUNK; e += 256) {
        int c = col[e], r = row[e];
        colW[e] = c; rowW[e] = r;
        atomicAdd(&hC[c >> SHIFT], 1u);
        atomicAdd(&hR[r >> SHIFT], 1u);
    }
    __syncthreads();
    if (threadIdx.x < NBK) {
        cmC[(size_t)threadIdx.x * WGC + w] = hC[threadIdx.x];
        cmR[(size_t)threadIdx.x * WGC + w] = hR[threadIdx.x];
    }
}

// ---- K2: exclusive prefix over WGs per bucket (one warp per bucket row)
__global__ void __launch_bounds__(256) k_prefix(
    unsigned* __restrict__ cmC, unsigned* __restrict__ cmR,
    unsigned* __restrict__ totC, unsigned* __restrict__ totR)
{
    int warp = (blockIdx.x * 256 + threadIdx.x) >> 6;
    int lane = threadIdx.x & 63;
    if (warp >= 2 * NBK) return;
    unsigned* cm  = (warp < NBK) ? cmC : cmR;
    unsigned* tot = (warp < NBK) ? totC : totR;
    int b = (warp < NBK) ? warp : warp - NBK;
    unsigned* rowp = cm + (size_t)b * WGC;
    unsigned carry = 0;
    for (int base = 0; base < WGC; base += 64) {
        int idx = base + lane;
        unsigned v = (idx < WGC) ? rowp[idx] : 0u;
        unsigned inc = v;
        for (int off = 1; off < 64; off <<= 1) {
            unsigned t = __shfl_up(inc, off, 64);
            if (lane >= off) inc += t;
        }
        if (idx < WGC) rowp[idx] = carry + inc - v;   // exclusive
        carry += __shfl(inc, 63, 64);
    }
    if (lane == 0) tot[b] = carry;
}

// ---- K3: tiny serial scans of 98 bucket totals -> bases
__global__ void __launch_bounds__(64) k_scan(
    const unsigned* __restrict__ totC, const unsigned* __restrict__ totR,
    unsigned* __restrict__ baseC, unsigned* __restrict__ baseR)
{
    if (threadIdx.x == 0) {
        unsigned s = 0;
        for (int b = 0; b < NBK; ++b) { baseC[b] = s; s += totC[b]; }
    } else if (threadIdx.x == 1) {
        unsigned s = 0;
        for (int b = 0; b < NBK; ++b) { baseR[b] = s; s += totR[b]; }
    }
}

// ---- K0: streaming compute on WS data only. Reads booB (bf16, 32B/edge,
//      dense, fast ws path) + vin gather (ws, L2-hit), writes 8B message.
template<int TRANS>
__global__ void __launch_bounds__(256) k_msg(
    const int* __restrict__ pay,       // ws copy of source index
    const float4* __restrict__ vin,    // xW (p1) or lt (p2), in ws
    const uint2* __restrict__ booB,    // bf16 A, [N_EDGES*4] uint2
    uint2* __restrict__ msgE)
{
    int e = blockIdx.x * 256 + threadIdx.x;
    if (e >= N_EDGES) return;
    float4 v = vin[pay[e]];
    uint2 w0 = booB[(size_t)e * 4 + 0];   // a00 a01 | a02 a03
    uint2 w1 = booB[(size_t)e * 4 + 1];   // a10 a11 | a12 a13
    uint2 w2 = booB[(size_t)e * 4 + 2];
    uint2 w3 = booB[(size_t)e * 4 + 3];
    float a00 = lo16(w0.x), a01 = hi16(w0.x), a02 = lo16(w0.y), a03 = hi16(w0.y);
    float a10 = lo16(w1.x), a11 = hi16(w1.x), a12 = lo16(w1.y), a13 = hi16(w1.y);
    float a20 = lo16(w2.x), a21 = hi16(w2.x), a22 = lo16(w2.y), a23 = hi16(w2.y);
    float a30 = lo16(w3.x), a31 = hi16(w3.x), a32 = lo16(w3.y), a33 = hi16(w3.y);
    float m0, m1, m2, m3;
    if (TRANS) {  // A^T v
        m0 = a00 * v.x + a10 * v.y + a20 * v.z + a30 * v.w;
        m1 = a01 * v.x + a11 * v.y + a21 * v.z + a31 * v.w;
        m2 = a02 * v.x + a12 * v.y + a22 * v.z + a32 * v.w;
        m3 = a03 * v.x + a13 * v.y + a23 * v.z + a33 * v.w;
    } else {      // A v
        m0 = a00 * v.x + a01 * v.y + a02 * v.z + a03 * v.w;
        m1 = a10 * v.x + a11 * v.y + a12 * v.z + a13 * v.w;
        m2 = a20 * v.x + a21 * v.y + a22 * v.z + a23 * v.w;
        m3 = a30 * v.x + a31 * v.y + a32 * v.z + a33 * v.w;
    }
    msgE[e] = make_uint2(pack2(m0, m1), pack2(m2, m3));
}

// ---- K4: partition messages into bucket-sorted split streams. LDS-staged,
//      runs ~33 records; all global stores word-sized; ws-only traffic.
__global__ void __launch_bounds__(256) k_part(
    const int* __restrict__ key,       // ws copy of destination index
    const uint2* __restrict__ msgE,
    const unsigned* __restrict__ cm,
    const unsigned* __restrict__ base,
    uint2* __restrict__ msgS,
    unsigned* __restrict__ locS)
{
    __shared__ uint2 smsg[CHUNK];           // 25.6 KB
    __shared__ unsigned short sloc[CHUNK];  // 6.4 KB
    __shared__ unsigned hist[NBK];
    __shared__ unsigned runstart[NBK + 1];
    __shared__ unsigned gdst[NBK];
    int w = blockIdx.x, tid = threadIdx.x, e0 = w * CHUNK;

    if (tid < NBK) {
        hist[tid] = 0u;
        gdst[tid] = base[tid] + cm[(size_t)tid * WGC + w];
    }
    __syncthreads();
    for (int e = e0 + tid; e < e0 + CHUNK; e += 256)
        atomicAdd(&hist[key[e] >> SHIFT], 1u);
    __syncthreads();
    if (tid == 0) {
        unsigned s = 0;
        for (int b = 0; b < NBK; ++b) { runstart[b] = s; s += hist[b]; }
        runstart[NBK] = s;
    }
    __syncthreads();
    if (tid < NBK) hist[tid] = runstart[tid];  // cursors
    __syncthreads();

    for (int e = e0 + tid; e < e0 + CHUNK; e += 256) {
        int k = key[e];
        int b = k >> SHIFT;
        unsigned pos = atomicAdd(&hist[b], 1u);
        smsg[pos] = msgE[e];
        sloc[pos] = (unsigned short)(k & (NPB - 1));
    }
    __syncthreads();

    for (int s = tid; s < CHUNK; s += 256) {
        int lo = 0, hi = NBK;
        while (hi - lo > 1) {
            int mid = (lo + hi) >> 1;
            if (runstart[mid] <= (unsigned)s) lo = mid; else hi = mid;
        }
        size_t g = (size_t)gdst[lo] + (unsigned)s - runstart[lo];
        msgS[g] = smsg[s];
        locS[g] = (unsigned)sloc[s];
    }
}

// ---- K5: PSPLIT contiguous spans per bucket: dense stream, 16KB LDS f32 acc
__global__ void __launch_bounds__(512) k_reduce(
    const uint2* __restrict__ msgS, const unsigned* __restrict__ locS,
    const unsigned* __restrict__ base, const unsigned* __restrict__ tot,
    float4* __restrict__ part)
{
    __shared__ float acc[4][NPB];
    int b = blockIdx.x / PSPLIT, sub = blockIdx.x % PSPLIT;
    int tid = threadIdx.x;
    for (int i = tid; i < 4 * NPB; i += 512) ((float*)acc)[i] = 0.f;
    __syncthreads();
    unsigned start = base[b], n = tot[b];
    unsigned lo = start + (unsigned)(((unsigned long long)n * sub) / PSPLIT);
    unsigned hi = start + (unsigned)(((unsigned long long)n * (sub + 1)) / PSPLIT);
    for (unsigned i = lo + tid; i < hi; i += 512) {
        uint2 m = msgS[i];
        int loc = (int)locS[i];
        atomicAdd(&acc[0][loc], lo16(m.x));
        atomicAdd(&acc[1][loc], hi16(m.x));
        atomicAdd(&acc[2][loc], lo16(m.y));
        atomicAdd(&acc[3][loc], hi16(m.y));
    }
    __syncthreads();
    float4* dst = part + (size_t)sub * SLOTS + (size_t)b * NPB;
    for (int i = tid; i < NPB; i += 512)
        dst[i] = make_float4(acc[0][i], acc[1][i], acc[2][i], acc[3][i]);
}

// ---- K6: merge PSPLIT partial buffers -> final vector
__global__ void __launch_bounds__(256) k_merge(
    const float4* __restrict__ part, float4* __restrict__ vout)
{
    int s = blockIdx.x * 256 + threadIdx.x;
    if (s >= N_NODES) return;
    float4 r = part[s];
    for (int sub = 1; sub < PSPLIT; ++sub) {
        float4 t = part[(size_t)sub * SLOTS + s];
        r.x += t.x; r.y += t.y; r.z += t.z; r.w += t.w;
    }
    vout[s] = r;
}

// ================= fallback path (R3: sector-merged global atomics) =================

__global__ void __launch_bounds__(256) llt_pass1(
    const float* __restrict__ x, const int* __restrict__ row_idx,
    const int* __restrict__ col_idx, const float* __restrict__ boo,
    float* __restrict__ lt)
{
    int t = blockIdx.x * blockDim.x + threadIdx.x;
    if (t >= N_EDGES * 4) return;
    int e = t >> 2, i = t & 3;
    int r = row_idx[e], c = col_idx[e];
    const float* A = boo + (size_t)e * 16;
    const float* xv = x + (size_t)r * 4;
    float m = A[0*4+i]*xv[0] + A[1*4+i]*xv[1] + A[2*4+i]*xv[2] + A[3*4+i]*xv[3];
    atomicAdd(lt + (size_t)c * 4 + i, m);
}

__global__ void __launch_bounds__(256) llt_pass2(
    const float4* __restrict__ lt, const int* __restrict__ row_idx,
    const int* __restrict__ col_idx, const float4* __restrict__ boo,
    float* __restrict__ out)
{
    int t = blockIdx.x * blockDim.x + threadIdx.x;
    if (t >= N_EDGES * 4) return;
    int e = t >> 2, i = t & 3;
    int r = row_idx[e], c = col_idx[e];
    float4 arow = boo[(size_t)e * 4 + i];
    float4 lv = lt[c];
    float m = arow.x*lv.x + arow.y*lv.y + arow.z*lv.z + arow.w*lv.w;
    atomicAdd(out + (size_t)r * 4 + i, m);
}

// ================= host =================

extern "C" void kernel_launch(void* const* d_in, const int* in_sizes, int n_in,
                              void* d_out, int out_size, void* d_ws, size_t ws_size,
                              hipStream_t stream) {
    const float4* x = (const float4*)d_in[0];        // [100000,4] f32
    const int* edge_index = (const int*)d_in[1];     // [2, 3200000] int32
    const float4* boo = (const float4*)d_in[2];      // [3200000,4,4] f32
    const int* row = edge_index;                     // edge_index[0]
    const int* col = edge_index + N_EDGES;           // edge_index[1]
    float4* out = (float4*)d_out;

    auto align256 = [](size_t v) { return (v + 255) & ~(size_t)255; };
    const size_t sz_cm   = align256((size_t)NBK * WGC * 4);       // 392 KB each
    const size_t sz_vec  = align256((size_t)NBK * 4);
    const size_t sz_booB = align256((size_t)N_EDGES * 32);        // 102.4 MB
    const size_t sz_idx  = align256((size_t)N_EDGES * 4);         // 12.8 MB each
    const size_t sz_x    = align256((size_t)N_NODES * 16);        // 1.6 MB
    const size_t sz_msgE = align256((size_t)N_EDGES * 8);         // 25.6 MB
    const size_t sz_msgS = align256((size_t)N_EDGES * 8);         // 25.6 MB
    const size_t sz_loc  = align256((size_t)N_EDGES * 4);         // 12.8 MB
    const size_t sz_lt   = align256((size_t)N_NODES * 16);        // 1.6 MB
    const size_t sz_part = align256((size_t)PSPLIT * SLOTS * 16); // 12.85 MB
    const size_t need = 2 * sz_cm + 4 * sz_vec + sz_booB + 2 * sz_idx + sz_x
                      + sz_msgE + sz_msgS + sz_loc + sz_lt + sz_part;

    if (ws_size >= need) {
        char* p = (char*)d_ws;
        unsigned* cmC   = (unsigned*)p; p += sz_cm;
        unsigned* cmR   = (unsigned*)p; p += sz_cm;
        unsigned* totC  = (unsigned*)p; p += sz_vec;
        unsigned* totR  = (unsigned*)p; p += sz_vec;
        unsigned* baseC = (unsigned*)p; p += sz_vec;
        unsigned* baseR = (unsigned*)p; p += sz_vec;
        uint2*    booB  = (uint2*)p;    p += sz_booB;
        int*      rowW  = (int*)p;      p += sz_idx;
        int*      colW  = (int*)p;      p += sz_idx;
        float4*   xW    = (float4*)p;   p += sz_x;
        uint2*    msgE  = (uint2*)p;    p += sz_msgE;
        uint2*    msgS  = (uint2*)p;    p += sz_msgS;
        unsigned* locS  = (unsigned*)p; p += sz_loc;
        float4*   lt    = (float4*)p;   p += sz_lt;
        float4*   part  = (float4*)p;   p += sz_part;

        const int mgrid = (N_EDGES + 255) / 256;
        const int igrid = (N_EDGES * 4 + 255) / 256;

        // import phase: d_in is touched exactly once per buffer
        k_import_x<<<(N_NODES + 255) / 256, 256, 0, stream>>>(x, xW);
        k_count<<<WGC, 256, 0, stream>>>(row, col, rowW, colW, cmC, cmR);
        k_prefix<<<(2 * NBK * 64 + 255) / 256, 256, 0, stream>>>(cmC, cmR, totC, totR);
        k_scan<<<1, 64, 0, stream>>>(totC, totR, baseC, baseR);
        k_import_boo<<<igrid, 256, 0, stream>>>(boo, booB);
        // pass 1: msg = A^T x[row], bucket by col -> lt
        k_msg<1><<<mgrid, 256, 0, stream>>>(rowW, xW, booB, msgE);
        k_part<<<WGC, 256, 0, stream>>>(colW, msgE, cmC, baseC, msgS, locS);
        k_reduce<<<NBK * PSPLIT, 512, 0, stream>>>(msgS, locS, baseC, totC, part);
        k_merge<<<(N_NODES + 255) / 256, 256, 0, stream>>>(part, lt);
        // pass 2: msg = A lt[col], bucket by row -> out
        k_msg<0><<<mgrid, 256, 0, stream>>>(colW, (const float4*)lt, booB, msgE);
        k_part<<<WGC, 256, 0, stream>>>(rowW, msgE, cmR, baseR, msgS, locS);
        k_reduce<<<NBK * PSPLIT, 512, 0, stream>>>(msgS, locS, baseR, totR, part);
        k_merge<<<(N_NODES + 255) / 256, 256, 0, stream>>>(part, out);
    } else {
        // fallback: sector-merged atomics (R3, 328 us)
        float* ltf = (float*)d_ws;
        hipMemsetAsync(ltf, 0, (size_t)N_NODES * 4 * sizeof(float), stream);
        hipMemsetAsync(out, 0, (size_t)N_NODES * 4 * sizeof(float), stream);
        const int grid = (N_EDGES * 4 + 255) / 256;
        llt_pass1<<<grid, 256, 0, stream>>>((const float*)x, row, col, (const float*)boo, ltf);
        llt_pass2<<<grid, 256, 0, stream>>>((const float4*)ltf, row, col, boo, (float*)out);
    }
}